// Round 3
// baseline (2355.755 us; speedup 1.0000x reference)
//
#include <hip/hip_runtime.h>
#include <stdint.h>

#define Bn  256
#define Hn  512
#define En  512
#define Vn  32000
#define Fn  512
#define HWn 256

typedef unsigned short u16;

__device__ __forceinline__ float b2f(u16 u) {
    union { unsigned int i; float f; } c; c.i = ((unsigned int)u) << 16; return c.f;
}
__device__ __forceinline__ u16 f2b(float f) {
    union { float f; unsigned int i; } c; c.f = f;
    unsigned int x = c.i;
    return (u16)((x + 0x7fffu + ((x >> 16) & 1u)) >> 16);
}
__device__ __forceinline__ float2 up2(unsigned int d) {
    union { unsigned int i; float f; } lo, hi;
    lo.i = d << 16; hi.i = d & 0xffff0000u;
    return make_float2(lo.f, hi.f);
}
__device__ __forceinline__ float sigm(float x) { return 1.0f / (1.0f + __expf(-x)); }

// dtype-flexible input loads: F32=0 -> storage bf16(u16); F32=1 -> storage f32
template<int F32> __device__ __forceinline__ float ldf(const void* p, int i) {
    if (F32) return ((const float*)p)[i];
    return b2f(((const u16*)p)[i]);
}
template<int F32> __device__ __forceinline__ u16 ldu(const void* p, int i) {
    if (F32) return f2b(((const float*)p)[i]);
    return ((const u16*)p)[i];
}

// ---------------------------------------------------------------------------
// K0: input dtype detector (hidden_state ~ N(0,1)).
// bf16 storage: ~99.9% of u16s decode to |x| in (1e-3,100) -> cnt ~4090
// f32 storage:  ~53% (odd u16s = real bf16 halves, even = mantissa junk) ~2100
__global__ void k_detect(const void* hidden, int* flag) {
    __shared__ int cnt[256];
    int tid = threadIdx.x, c = 0;
    for (int i = tid; i < 4096; i += 256) {
        float a = fabsf(b2f(((const u16*)hidden)[i]));
        if (a > 0.001f && a < 100.f) c++;
    }
    cnt[tid] = c; __syncthreads();
    for (int off = 128; off; off >>= 1) {
        if (tid < off) cnt[tid] += cnt[tid + off];
        __syncthreads();
    }
    if (tid == 0) *flag = (cnt[0] > 3500) ? 0 : 1;   // 0=bf16, 1=f32
}

// ---------------------------------------------------------------------------
// K1: ht[b,h] = hidden[b,:]@Whw[h,:] + Whb[h] + WFb[h]
template<int F32>
__global__ void k_ht(const int* __restrict__ flag, const void* __restrict__ hidden,
                     const void* __restrict__ Whw, const void* __restrict__ Whb,
                     const void* __restrict__ WFb, float* __restrict__ ht) {
    if (*flag != F32) return;
    __shared__ float hs[Hn];
    int b = blockIdx.x >> 1, htile = blockIdx.x & 1, tid = threadIdx.x;
    for (int k = tid; k < Hn; k += 256) hs[k] = ldf<F32>(hidden, b * Hn + k);
    __syncthreads();
    int h = htile * 256 + tid;
    float acc = 0.f;
    for (int k = 0; k < Hn; k++) acc += hs[k] * ldf<F32>(Whw, h * Hn + k);
    ht[b * Hn + h] = acc + ldf<F32>(Whb, h) + ldf<F32>(WFb, h);
}

// ---------------------------------------------------------------------------
// K2: sc[b,i] = (1/51.2) * sum_h tanh(ht[b,h] + sum_f flat[b,f,i]*WFw[h,f])
// block: (b, itile of 32). 256 thr = 16 ii x 16 hh, 2 i per thread.
// LDS rows padded to 520 (1040 B = 16B-aligned, bank-stride 4 -> <=2-way, free)
template<int F32>
__global__ __launch_bounds__(256) void k_scores(const int* __restrict__ flag,
                                                const void* __restrict__ flat,
                                                const void* __restrict__ WFw,
                                                const float* __restrict__ ht,
                                                float* __restrict__ sc) {
    if (*flag != F32) return;
    __shared__ __align__(16) u16 Al[32][520];
    __shared__ __align__(16) u16 Wl[16][520];
    int b = blockIdx.x, it = blockIdx.y, tid = threadIdx.x;
    int ibase = it * 32;
    int fbase = b * (Fn * HWn) + ibase;
    for (int r = 0; r < 64; r++) {                  // Al[il][f] = flat[b,f,ibase+il]
        int idx = r * 256 + tid;
        int il = idx & 31, f = idx >> 5;
        Al[il][f] = ldu<F32>(flat, fbase + f * HWn + il);
    }
    int ii = tid >> 4, hh = tid & 15;
    int i0 = 2 * ii, i1 = 2 * ii + 1;
    const uint4* ar0 = (const uint4*)&Al[i0][0];
    const uint4* ar1 = (const uint4*)&Al[i1][0];
    const uint4* wr  = (const uint4*)&Wl[hh][0];
    float part0 = 0.f, part1 = 0.f;
    for (int hc = 0; hc < 32; hc++) {
        __syncthreads();
        for (int r = 0; r < 32; r++) {              // Wl[hl][f] = WFw[hc*16+hl, f]
            int idx = r * 256 + tid;
            int f = idx & 511, hl = idx >> 9;
            Wl[hl][f] = ldu<F32>(WFw, (hc * 16 + hl) * Fn + f);
        }
        __syncthreads();
        float a0 = 0.f, a1 = 0.f;
        #pragma unroll 8
        for (int c = 0; c < 64; c++) {
            uint4 w4 = wr[c], x0 = ar0[c], x1 = ar1[c];
            float2 w0 = up2(w4.x), w1 = up2(w4.y), w2 = up2(w4.z), w3 = up2(w4.w);
            float2 p0 = up2(x0.x), p1 = up2(x0.y), p2 = up2(x0.z), p3 = up2(x0.w);
            float2 q0 = up2(x1.x), q1 = up2(x1.y), q2 = up2(x1.z), q3 = up2(x1.w);
            a0 += p0.x*w0.x + p0.y*w0.y + p1.x*w1.x + p1.y*w1.y
                + p2.x*w2.x + p2.y*w2.y + p3.x*w3.x + p3.y*w3.y;
            a1 += q0.x*w0.x + q0.y*w0.y + q1.x*w1.x + q1.y*w1.y
                + q2.x*w2.x + q2.y*w2.y + q3.x*w3.x + q3.y*w3.y;
        }
        float base = ht[b * Hn + hc * 16 + hh];     // L1-broadcast
        part0 += tanhf(base + a0);
        part1 += tanhf(base + a1);
    }
    __syncthreads();                                // done reading Wl
    float* red = (float*)&Wl[0][0];                 // reuse Wl LDS as red[32][16]
    red[i0 * 16 + hh] = part0;
    red[i1 * 16 + hh] = part1;
    __syncthreads();
    if (tid < 32) {
        float s = 0.f;
        for (int k = 0; k < 16; k++) s += red[tid * 16 + k];
        sc[b * HWn + ibase + tid] = s * (1.0f / 51.2f);
    }
}

// ---------------------------------------------------------------------------
// K3: attn = softmax_i(sc[b,:]);  ctx[b,f] = sum_i attn[i]*flat[b,f,i]
template<int F32>
__global__ void k_attn_ctx(const int* __restrict__ flag, const float* __restrict__ sc,
                           const void* __restrict__ flat, float* __restrict__ ctx) {
    if (*flag != F32) return;
    __shared__ float sa[HWn], r1[HWn];
    int b = blockIdx.x, tid = threadIdx.x;
    float x = sc[b * HWn + tid];
    r1[tid] = x; __syncthreads();
    for (int off = 128; off; off >>= 1) {
        if (tid < off) r1[tid] = fmaxf(r1[tid], r1[tid + off]);
        __syncthreads();
    }
    float M = r1[0];
    __syncthreads();
    float e = __expf(x - M);
    r1[tid] = e; __syncthreads();
    for (int off = 128; off; off >>= 1) {
        if (tid < off) r1[tid] += r1[tid + off];
        __syncthreads();
    }
    sa[tid] = e / r1[0];
    __syncthreads();
    int fb = b * (Fn * HWn);
    for (int f = tid; f < Fn; f += 256) {
        int row = fb + f * HWn;
        float acc = 0.f;
        for (int i = 0; i < HWn; i++) acc += sa[i] * ldf<F32>(flat, row + i);
        ctx[b * Fn + f] = acc;
    }
}

// ---------------------------------------------------------------------------
// K4: gates[b,j] = bih[j]+bhh[j] + tok@Wih[j,:512] + ctx@Wih[j,512:] + hid@Whh[j,:]
template<int F32>
__global__ void k_gates(const int* __restrict__ flag, const void* __restrict__ tok,
                        const float* __restrict__ ctx, const void* __restrict__ hid,
                        const void* __restrict__ Wih, const void* __restrict__ bih,
                        const void* __restrict__ Whh, const void* __restrict__ bhh,
                        float* __restrict__ gates) {
    if (*flag != F32) return;
    __shared__ float xt[En], xc[Hn], xh[Hn];
    int b = blockIdx.x, jt = blockIdx.y, tid = threadIdx.x;
    for (int k = tid; k < En; k += 256) xt[k] = ldf<F32>(tok, b * En + k);
    for (int k = tid; k < Hn; k += 256) {
        xc[k] = ctx[b * Fn + k];
        xh[k] = ldf<F32>(hid, b * Hn + k);
    }
    __syncthreads();
    int j = jt * 256 + tid;
    int wi = j * (En + Hn), wh = j * Hn;
    float acc = ldf<F32>(bih, j) + ldf<F32>(bhh, j);
    for (int k = 0; k < En; k++) acc += xt[k] * ldf<F32>(Wih, wi + k);
    for (int k = 0; k < Hn; k++) acc += xc[k] * ldf<F32>(Wih, wi + En + k);
    for (int k = 0; k < Hn; k++) acc += xh[k] * ldf<F32>(Whh, wh + k);
    gates[b * 2048 + j] = acc;
}

// ---------------------------------------------------------------------------
// K5: LSTM cell elementwise -> f32 outputs
template<int F32>
__global__ void k_lstm(const int* __restrict__ flag, const float* __restrict__ gates,
                       const void* __restrict__ cell, float* __restrict__ oh,
                       float* __restrict__ oc) {
    if (*flag != F32) return;
    int idx = blockIdx.x * 256 + threadIdx.x;
    int b = idx >> 9, h = idx & 511;
    const float* g = gates + b * 2048;
    float gi = g[h], gf = g[512 + h], gg = g[1024 + h], go = g[1536 + h];
    float c = ldf<F32>(cell, idx);
    float cn = sigm(gf) * c + sigm(gi) * tanhf(gg);
    float hv = sigm(go) * tanhf(cn);
    oh[idx] = hv;
    oc[idx] = cn;
}

// ---------------------------------------------------------------------------
// K6: logits[b,v] = h_new[b,:]@Wow[v,:] + Wob[v]
// block: 32 b x 16 v. 256 thr = 16 bb x 16 vl, 2 b per thread.
template<int F32>
__global__ __launch_bounds__(256) void k_out(const int* __restrict__ flag,
                                             const float* __restrict__ hnew,
                                             const void* __restrict__ Wow,
                                             const void* __restrict__ Wob,
                                             float* __restrict__ outl) {
    if (*flag != F32) return;
    __shared__ __align__(16) u16 hl[32][520];
    __shared__ __align__(16) u16 wl[16][520];
    int b0 = blockIdx.x * 32, v0 = blockIdx.y * 16, tid = threadIdx.x;
    for (int r = 0; r < 64; r++) {
        int idx = r * 256 + tid;
        int k = idx & 511, bl = idx >> 9;
        hl[bl][k] = f2b(hnew[(b0 + bl) * Hn + k]);
    }
    for (int r = 0; r < 32; r++) {
        int idx = r * 256 + tid;
        int k = idx & 511, vl = idx >> 9;
        wl[vl][k] = ldu<F32>(Wow, (v0 + vl) * Hn + k);
    }
    __syncthreads();
    int bb = tid >> 4, vl = tid & 15;
    const uint4* hr0 = (const uint4*)&hl[bb][0];
    const uint4* hr1 = (const uint4*)&hl[bb + 16][0];
    const uint4* wr  = (const uint4*)&wl[vl][0];
    float a0 = 0.f, a1 = 0.f;
    #pragma unroll 8
    for (int c = 0; c < 64; c++) {
        uint4 w4 = wr[c], x0 = hr0[c], x1 = hr1[c];
        float2 w0 = up2(w4.x), w1 = up2(w4.y), w2 = up2(w4.z), w3 = up2(w4.w);
        float2 p0 = up2(x0.x), p1 = up2(x0.y), p2 = up2(x0.z), p3 = up2(x0.w);
        float2 q0 = up2(x1.x), q1 = up2(x1.y), q2 = up2(x1.z), q3 = up2(x1.w);
        a0 += p0.x*w0.x + p0.y*w0.y + p1.x*w1.x + p1.y*w1.y
            + p2.x*w2.x + p2.y*w2.y + p3.x*w3.x + p3.y*w3.y;
        a1 += q0.x*w0.x + q0.y*w0.y + q1.x*w1.x + q1.y*w1.y
            + q2.x*w2.x + q2.y*w2.y + q3.x*w3.x + q3.y*w3.y;
    }
    int v = v0 + vl;
    float bias = ldf<F32>(Wob, v);
    outl[(b0 + bb) * Vn + v] = a0 + bias;
    outl[(b0 + bb + 16) * Vn + v] = a1 + bias;
}

// ---------------------------------------------------------------------------
// K7: row softmax over V (f32 logits from d_out -> f32 probs)
__global__ void k_vsoftmax(const float* __restrict__ logits, float* __restrict__ probs) {
    __shared__ float rm[256], rs[256];
    int b = blockIdx.x, tid = threadIdx.x;
    const float* row = logits + (size_t)b * Vn;
    float m = -1e30f, s = 0.f;
    for (int v = tid; v < Vn; v += 256) {
        float x = row[v];
        if (x > m) { s = s * __expf(m - x); m = x; }
        s += __expf(x - m);
    }
    rm[tid] = m; rs[tid] = s; __syncthreads();
    for (int off = 128; off; off >>= 1) {
        if (tid < off) {
            float m2 = rm[tid + off], s2 = rs[tid + off];
            float M = fmaxf(rm[tid], m2);
            rs[tid] = rs[tid] * __expf(rm[tid] - M) + s2 * __expf(m2 - M);
            rm[tid] = M;
        }
        __syncthreads();
    }
    float M = rm[0], S = rs[0];
    float* prow = probs + (size_t)b * Vn;
    for (int v = tid; v < Vn; v += 256) prow[v] = __expf(row[v] - M) / S;
}

// ---------------------------------------------------------------------------
extern "C" void kernel_launch(void* const* d_in, const int* in_sizes, int n_in,
                              void* d_out, int out_size, void* d_ws, size_t ws_size,
                              hipStream_t stream) {
    const void* tok    = d_in[0];
    const void* hidden = d_in[1];
    const void* cell   = d_in[2];
    const void* img    = d_in[3];
    const void* Whw    = d_in[4];
    const void* Whb    = d_in[5];
    const void* WFw    = d_in[6];
    const void* WFb    = d_in[7];
    const void* Wih    = d_in[8];
    const void* bih    = d_in[9];
    const void* Whh    = d_in[10];
    const void* bhh    = d_in[11];
    const void* Wow    = d_in[12];
    const void* Wob    = d_in[13];

    float* out = (float*)d_out;
    float* out_probs  = out;                              // [B*V]
    float* out_h      = out + (size_t)Bn * Vn;            // [B*H]
    float* out_c      = out_h + (size_t)Bn * Hn;          // [B*H]
    float* out_logits = out_c + (size_t)Bn * Hn;          // [B*V]

    float* ws    = (float*)d_ws;
    int* flag    = (int*)d_ws;
    float* ht    = ws + 64;           // 131072
    float* sc    = ht + 131072;       // 65536
    float* ctx   = sc + 65536;        // 131072
    float* gates = ctx + 131072;      // 524288  (total ~3.4 MB)

    k_detect<<<dim3(1), 256, 0, stream>>>(hidden, flag);

    k_ht<0><<<dim3(512), 256, 0, stream>>>(flag, hidden, Whw, Whb, WFb, ht);
    k_ht<1><<<dim3(512), 256, 0, stream>>>(flag, hidden, Whw, Whb, WFb, ht);
    k_scores<0><<<dim3(256, 8), 256, 0, stream>>>(flag, img, WFw, ht, sc);
    k_scores<1><<<dim3(256, 8), 256, 0, stream>>>(flag, img, WFw, ht, sc);
    k_attn_ctx<0><<<dim3(256), 256, 0, stream>>>(flag, sc, img, ctx);
    k_attn_ctx<1><<<dim3(256), 256, 0, stream>>>(flag, sc, img, ctx);
    k_gates<0><<<dim3(256, 8), 256, 0, stream>>>(flag, tok, ctx, hidden, Wih, bih, Whh, bhh, gates);
    k_gates<1><<<dim3(256, 8), 256, 0, stream>>>(flag, tok, ctx, hidden, Wih, bih, Whh, bhh, gates);
    k_lstm<0><<<dim3(512), 256, 0, stream>>>(flag, gates, cell, out_h, out_c);
    k_lstm<1><<<dim3(512), 256, 0, stream>>>(flag, gates, cell, out_h, out_c);
    k_out<0><<<dim3(8, 2000), 256, 0, stream>>>(flag, out_h, Wow, Wob, out_logits);
    k_out<1><<<dim3(8, 2000), 256, 0, stream>>>(flag, out_h, Wow, Wob, out_logits);

    k_vsoftmax<<<dim3(256), 256, 0, stream>>>(out_logits, out_probs);
}

// Round 4
// 646.288 us; speedup vs baseline: 3.6451x; 3.6451x over previous
//
#include <hip/hip_runtime.h>
#include <stdint.h>

#define Bn  256
#define Hn  512
#define En  512
#define Vn  32000
#define Fn  512
#define HWn 256

typedef unsigned short u16;
typedef unsigned int u32;
typedef __attribute__((ext_vector_type(4))) float f32x4;
typedef __attribute__((ext_vector_type(8))) short bf16x8;

__device__ __forceinline__ u16 hi16(float x) {
    return (u16)((__float_as_uint(x) + 0x8000u) >> 16);
}
__device__ __forceinline__ u32 pack2(float a, float b) {
    return ((__float_as_uint(a) + 0x8000u) >> 16) |
           ((__float_as_uint(b) + 0x8000u) & 0xffff0000u);
}
__device__ __forceinline__ float sigm(float x) { return 1.0f / (1.0f + __expf(-x)); }
__device__ __forceinline__ float tanh_fast(float x) {
    x = fminf(15.f, fmaxf(-15.f, x));
    float e = __expf(2.f * x);
    return 1.f - 2.f / (e + 1.f);
}

// ---------------------------------------------------------------------------
// zero sc (ws is 0xAA-poisoned; k_scores accumulates into sc with atomics)
__global__ void k_zero(float* __restrict__ p) {
    ((float4*)p)[blockIdx.x * 256 + threadIdx.x] = make_float4(0.f, 0.f, 0.f, 0.f);
}

// ---------------------------------------------------------------------------
// Generic MFMA GEMM: out[m, n] = sum_seg A_s[m,:512] . W_s[n, koff:koff+512] + biases
// M = 256 (4 btiles x 64), N tiles of 32 (blockIdx.y). 512 thr = 8 waves,
// wave w: m-tile = w&3 (16 rows), n-tile = w>>2 (16 cols). K chunks of 128.
// LDS rows padded to 136 elems (272 B = 17*16: b128-aligned, bank stride 4).
__global__ __launch_bounds__(512) void k_gemm(
    const float* __restrict__ A0, const float* __restrict__ A1, const float* __restrict__ A2,
    const float* __restrict__ W0, const float* __restrict__ W1, const float* __restrict__ W2,
    int ws0, int ws1, int ws2, int ko0, int ko1, int ko2, int nseg,
    const float* __restrict__ bias1, const float* __restrict__ bias2,
    float* __restrict__ out, int ostride)
{
    __shared__ u16 Al[64 * 136];
    __shared__ u16 Wl[32 * 136];
    int tid = threadIdx.x;
    int b0 = blockIdx.x * 64, n0 = blockIdx.y * 32;
    int w = tid >> 6, lane = tid & 63, lm = lane & 15, quad = lane >> 4;
    int ti = w & 3, nt = w >> 2;
    const float* As[3] = {A0, A1, A2};
    const float* Ws[3] = {W0, W1, W2};
    int wss[3] = {ws0, ws1, ws2};
    int kos[3] = {ko0, ko1, ko2};
    f32x4 ae = {0.f, 0.f, 0.f, 0.f}, ao = {0.f, 0.f, 0.f, 0.f};
    int ra = ti * 16 + lm, rw = nt * 16 + lm;
    for (int s = 0; s < nseg; s++) {
        const float* Ap = As[s];
        const float* Wp = Ws[s];
        int wstr = wss[s], koff = kos[s];
        for (int kc = 0; kc < 4; kc++) {
            __syncthreads();
            #pragma unroll
            for (int i = 0; i < 4; i++) {          // A: 64 rows x 128 k
                int idx4 = i * 512 + tid;
                int k4 = (idx4 & 31) * 4;
                int row = idx4 >> 5;
                float4 v = *(const float4*)(Ap + (b0 + row) * 512 + kc * 128 + k4);
                u32 lo = pack2(v.x, v.y), hi = pack2(v.z, v.w);
                *(uint2*)&Al[row * 136 + k4] = make_uint2(lo, hi);
            }
            #pragma unroll
            for (int i = 0; i < 2; i++) {          // W: 32 rows x 128 k
                int idx4 = i * 512 + tid;
                int k4 = (idx4 & 31) * 4;
                int row = idx4 >> 5;
                float4 v = *(const float4*)(Wp + (size_t)(n0 + row) * wstr + koff + kc * 128 + k4);
                u32 lo = pack2(v.x, v.y), hi = pack2(v.z, v.w);
                *(uint2*)&Wl[row * 136 + k4] = make_uint2(lo, hi);
            }
            __syncthreads();
            #pragma unroll
            for (int ks = 0; ks < 4; ks += 2) {
                bf16x8 a0 = *(const bf16x8*)&Al[ra * 136 + ks * 32 + quad * 8];
                bf16x8 w0 = *(const bf16x8*)&Wl[rw * 136 + ks * 32 + quad * 8];
                ae = __builtin_amdgcn_mfma_f32_16x16x32_bf16(a0, w0, ae, 0, 0, 0);
                bf16x8 a1 = *(const bf16x8*)&Al[ra * 136 + (ks + 1) * 32 + quad * 8];
                bf16x8 w1 = *(const bf16x8*)&Wl[rw * 136 + (ks + 1) * 32 + quad * 8];
                ao = __builtin_amdgcn_mfma_f32_16x16x32_bf16(a1, w1, ao, 0, 0, 0);
            }
        }
    }
    int n = n0 + nt * 16 + lm;
    float bias = bias1[n] + (bias2 ? bias2[n] : 0.f);
    #pragma unroll
    for (int r = 0; r < 4; r++) {
        int m = b0 + ti * 16 + quad * 4 + r;       // D: col=lane&15, row=quad*4+reg
        out[(size_t)m * ostride + n] = ae[r] + ao[r] + bias;
    }
}

// ---------------------------------------------------------------------------
// K2 (MFMA): sc[b,i] += (1/51.2) * sum_h tanh(ht[b,h] + sum_f flat[b,f,i]*WFw[h,f])
// block (b, it): i-tile 32, h-chunks of 32, 256 thr = 4 waves (2 i16 x 2 h16).
// Al/Wl: 32x512 bf16, XOR-swizzled at 8-elem granularity (16B), exactly 64 KB.
__device__ __forceinline__ int swz(int row, int kb, int j) {
    return row * 512 + ((kb ^ (row & 7)) << 3) + j;
}
__global__ __launch_bounds__(256) void k_scores(const float* __restrict__ flat,
                                                const float* __restrict__ WFw,
                                                const float* __restrict__ ht,
                                                float* __restrict__ sc) {
    __shared__ u16 Al[32 * 512];
    __shared__ u16 Wl[32 * 512];
    int b = blockIdx.x, it = blockIdx.y, tid = threadIdx.x;
    int i0 = it * 32;
    // stage A-tile: Al[il][f] = flat[b, f, i0+il], coalesced float4 over il
    const float* fbp = flat + (size_t)b * (Fn * HWn) + i0;
    #pragma unroll
    for (int i = 0; i < 16; i++) {
        int idx4 = i * 256 + tid;
        int il4 = (idx4 & 7) * 4;
        int f = idx4 >> 3;
        float4 v = *(const float4*)(fbp + f * HWn + il4);
        int kb = f >> 3, j = f & 7;
        Al[swz(il4 + 0, kb, j)] = hi16(v.x);
        Al[swz(il4 + 1, kb, j)] = hi16(v.y);
        Al[swz(il4 + 2, kb, j)] = hi16(v.z);
        Al[swz(il4 + 3, kb, j)] = hi16(v.w);
    }
    int w = tid >> 6, lane = tid & 63, lm = lane & 15, quad = lane >> 4;
    int ti = w & 1, hhalf = w >> 1;
    int ra = ti * 16 + lm, rax = ra & 7;
    int rw = hhalf * 16 + lm, rwx = rw & 7;
    float part[4] = {0.f, 0.f, 0.f, 0.f};
    for (int hc = 0; hc < 16; hc++) {
        __syncthreads();
        const float* wb = WFw + (size_t)(hc * 32) * Fn;
        #pragma unroll
        for (int i = 0; i < 16; i++) {             // Wl[hl][f] = WFw[hc*32+hl, f]
            int idx4 = i * 256 + tid;
            int f0 = (idx4 & 127) * 4;
            int hl = idx4 >> 7;
            float4 v = *(const float4*)(wb + hl * Fn + f0);
            u32 lo = pack2(v.x, v.y), hi = pack2(v.z, v.w);
            *(uint2*)&Wl[hl * 512 + (((f0 >> 3) ^ (hl & 7)) << 3) + (f0 & 7)] = make_uint2(lo, hi);
        }
        __syncthreads();
        f32x4 ae = {0.f, 0.f, 0.f, 0.f}, ao = {0.f, 0.f, 0.f, 0.f};
        #pragma unroll
        for (int ks = 0; ks < 16; ks += 2) {
            int kb0 = ks * 4 + quad, kb1 = kb0 + 4;
            bf16x8 a0 = *(const bf16x8*)&Al[ra * 512 + ((kb0 ^ rax) << 3)];
            bf16x8 w0 = *(const bf16x8*)&Wl[rw * 512 + ((kb0 ^ rwx) << 3)];
            ae = __builtin_amdgcn_mfma_f32_16x16x32_bf16(a0, w0, ae, 0, 0, 0);
            bf16x8 a1 = *(const bf16x8*)&Al[ra * 512 + ((kb1 ^ rax) << 3)];
            bf16x8 w1 = *(const bf16x8*)&Wl[rw * 512 + ((kb1 ^ rwx) << 3)];
            ao = __builtin_amdgcn_mfma_f32_16x16x32_bf16(a1, w1, ao, 0, 0, 0);
        }
        float base = ht[b * Hn + hc * 32 + hhalf * 16 + lm];
        #pragma unroll
        for (int r = 0; r < 4; r++)
            part[r] += tanh_fast(base + ae[r] + ao[r]);
    }
    #pragma unroll
    for (int r = 0; r < 4; r++) {
        float p = part[r];
        p += __shfl_xor(p, 1); p += __shfl_xor(p, 2);
        p += __shfl_xor(p, 4); p += __shfl_xor(p, 8);
        if (lm == 0)
            atomicAdd(&sc[b * HWn + i0 + ti * 16 + quad * 4 + r], p * (1.0f / 51.2f));
    }
}

// ---------------------------------------------------------------------------
// K3: attn = softmax_i(sc[b,:]); ctx[b,f] = sum_i attn[i]*flat[b,f,i]
// ctx phase: wave per f-row stripe, float4 coalesced + shuffle reduce.
__global__ void k_attn_ctx(const float* __restrict__ sc, const float* __restrict__ flat,
                           float* __restrict__ ctx) {
    __shared__ float sa[HWn], r1[HWn];
    int b = blockIdx.x, tid = threadIdx.x;
    float x = sc[b * HWn + tid];
    r1[tid] = x; __syncthreads();
    for (int off = 128; off; off >>= 1) {
        if (tid < off) r1[tid] = fmaxf(r1[tid], r1[tid + off]);
        __syncthreads();
    }
    float M = r1[0];
    __syncthreads();
    float e = __expf(x - M);
    r1[tid] = e; __syncthreads();
    for (int off = 128; off; off >>= 1) {
        if (tid < off) r1[tid] += r1[tid + off];
        __syncthreads();
    }
    sa[tid] = e / r1[0];
    __syncthreads();
    int w = tid >> 6, lane = tid & 63;
    const float4* f4 = (const float4*)(flat + (size_t)b * (Fn * HWn));
    const float4* s4 = (const float4*)sa;
    float4 sv = s4[lane];
    for (int f = w; f < Fn; f += 4) {
        float4 v = f4[f * 64 + lane];
        float acc = v.x * sv.x + v.y * sv.y + v.z * sv.z + v.w * sv.w;
        acc += __shfl_xor(acc, 32); acc += __shfl_xor(acc, 16);
        acc += __shfl_xor(acc, 8);  acc += __shfl_xor(acc, 4);
        acc += __shfl_xor(acc, 2);  acc += __shfl_xor(acc, 1);
        if (lane == 0) ctx[b * Fn + f] = acc;
    }
}

// ---------------------------------------------------------------------------
// K5: LSTM cell elementwise
__global__ void k_lstm(const float* __restrict__ gates, const float* __restrict__ cell,
                       float* __restrict__ oh, float* __restrict__ oc) {
    int idx = blockIdx.x * 256 + threadIdx.x;
    int b = idx >> 9, h = idx & 511;
    const float* g = gates + b * 2048;
    float gi = g[h], gf = g[512 + h], gg = g[1024 + h], go = g[1536 + h];
    float c = cell[idx];
    float cn = sigm(gf) * c + sigm(gi) * tanhf(gg);
    float hv = sigm(go) * tanhf(cn);
    oh[idx] = hv;
    oc[idx] = cn;
}

// ---------------------------------------------------------------------------
// K7: row softmax over V
__global__ void k_vsoftmax(const float* __restrict__ logits, float* __restrict__ probs) {
    __shared__ float rm[256], rs[256];
    int b = blockIdx.x, tid = threadIdx.x;
    const float* row = logits + (size_t)b * Vn;
    float m = -1e30f, s = 0.f;
    for (int v = tid; v < Vn; v += 256) {
        float x = row[v];
        if (x > m) { s = s * __expf(m - x); m = x; }
        s += __expf(x - m);
    }
    rm[tid] = m; rs[tid] = s; __syncthreads();
    for (int off = 128; off; off >>= 1) {
        if (tid < off) {
            float m2 = rm[tid + off], s2 = rs[tid + off];
            float M = fmaxf(rm[tid], m2);
            rs[tid] = rs[tid] * __expf(rm[tid] - M) + s2 * __expf(m2 - M);
            rm[tid] = M;
        }
        __syncthreads();
    }
    float M = rm[0], S = rs[0];
    float* prow = probs + (size_t)b * Vn;
    for (int v = tid; v < Vn; v += 256) prow[v] = __expf(row[v] - M) / S;
}

// ---------------------------------------------------------------------------
extern "C" void kernel_launch(void* const* d_in, const int* in_sizes, int n_in,
                              void* d_out, int out_size, void* d_ws, size_t ws_size,
                              hipStream_t stream) {
    const float* tok    = (const float*)d_in[0];
    const float* hidden = (const float*)d_in[1];
    const float* cell   = (const float*)d_in[2];
    const float* img    = (const float*)d_in[3];
    const float* Whw    = (const float*)d_in[4];
    const float* Whb    = (const float*)d_in[5];
    const float* WFw    = (const float*)d_in[6];
    const float* WFb    = (const float*)d_in[7];
    const float* Wih    = (const float*)d_in[8];
    const float* bih    = (const float*)d_in[9];
    const float* Whh    = (const float*)d_in[10];
    const float* bhh    = (const float*)d_in[11];
    const float* Wow    = (const float*)d_in[12];
    const float* Wob    = (const float*)d_in[13];

    float* out = (float*)d_out;
    float* out_probs  = out;                              // [B*V]
    float* out_h      = out + (size_t)Bn * Vn;            // [B*H]
    float* out_c      = out_h + (size_t)Bn * Hn;          // [B*H]
    float* out_logits = out_c + (size_t)Bn * Hn;          // [B*V]

    float* ws    = (float*)d_ws;
    float* ht    = ws;                // 131072 floats
    float* sc    = ht + 131072;       // 65536
    float* ctx   = sc + 65536;        // 131072
    float* gates = ctx + 131072;      // 524288  (total ~3.4 MB)

    k_zero<<<dim3(64), 256, 0, stream>>>(sc);

    // ht = hidden @ Whw^T + Whb + WFb
    k_gemm<<<dim3(4, 16), 512, 0, stream>>>(
        hidden, nullptr, nullptr, Whw, nullptr, nullptr,
        512, 0, 0, 0, 0, 0, 1, Whb, WFb, ht, 512);

    k_scores<<<dim3(256, 8), 256, 0, stream>>>(img, WFw, ht, sc);
    k_attn_ctx<<<dim3(256), 256, 0, stream>>>(sc, img, ctx);

    // gates = [tok|ctx] @ Wih^T + hid @ Whh^T + bih + bhh
    k_gemm<<<dim3(4, 64), 512, 0, stream>>>(
        tok, ctx, hidden, Wih, Wih, Whh,
        1024, 1024, 512, 0, 512, 0, 3, bih, bhh, gates, 2048);

    k_lstm<<<dim3(512), 256, 0, stream>>>(gates, cell, out_h, out_c);

    // logits = h_new @ Wow^T + Wob
    k_gemm<<<dim3(4, 1000), 512, 0, stream>>>(
        out_h, nullptr, nullptr, Wow, nullptr, nullptr,
        512, 0, 0, 0, 0, 0, 1, Wob, nullptr, out_logits, Vn);

    k_vsoftmax<<<dim3(256), 256, 0, stream>>>(out_logits, out_probs);
}